// Round 18
// baseline (101.329 us; speedup 1.0000x reference)
//
#include <hip/hip_runtime.h>

// SEIR SDE: B=32768 x 1000 steps -> out[step][4][B] f32 = 524 MB (write-bound).
// Ladder: 242 -> 115.6 -> 97.2 (R7 producer/consumer) -> 94.2 (R12 counted-
// vmcnt store reg-sets) -> 89.45 (R17: 512B store segments, component-pair
// store waves, 1 block/CU). Current: 214.7 cyc/CU/step vs 183 HBM floor.
// Store side is at its layout optimum (512B is the max contiguous segment at
// grid=256); fill side is the remaining lever. R16's fma fusion was
// confounded with the bad noise hoist; R18 isolates it on R17's structure:
// u=fma(btnD,P,sqrt(P)*wx) etc. -> 23->15 VALU/step, shorter dep chain.
// Numerics already validated: R16 ran this algebra, absmax 0.0.

constexpr int   B_TRAJ  = 32768;
constexpr int   NSTEPS  = 1000;
constexpr int   K       = 20;            // steps per chunk
constexpr int   NC      = NSTEPS / K;    // 50 chunks (even)
constexpr int   TPB     = 128;           // trajectories per block
constexpr float DT      = 0.01f;
constexpr float EPS     = 1e-6f;
constexpr float INV_N   = 1.0f / 10000.0f;

// Barrier without vmcnt drain: LDS ordering only; global stores stay in
// flight across chunk boundaries.
__device__ __forceinline__ void barrier_lds_only() {
    asm volatile("s_waitcnt lgkmcnt(0)" ::: "memory");
    __builtin_amdgcn_s_barrier();
    asm volatile("" ::: "memory");
}

__global__ __launch_bounds__(256) void seir_sde_kernel(
    const float* __restrict__ beta,
    const float* __restrict__ sigma,
    const float* __restrict__ gamma,
    const float* __restrict__ S0,
    const float* __restrict__ E0,
    const float* __restrict__ I0,
    const float* __restrict__ R0,
    const float4* __restrict__ dW,   // [NSTEPS] raw (w0,w1,w2,w3)
    float* __restrict__ out)         // [NSTEPS][4][B_TRAJ]
{
    __shared__ float4 wbuf[NSTEPS];          // pre-scaled noise, 16 KB
    __shared__ float  ring[2][K][4][TPB];    // SoA chunk ring, 80 KB
                                             // 96 KB total -> 1 block/CU

    // Folded constants (3 scalar loads, once, all threads).
    const float btnD = beta[0] * INV_N * DT; // (beta/N)*DT
    const float sgD  = sigma[0] * DT;        // sigma*DT
    const float gmD  = gamma[0] * DT;        // gamma*DT
    const float sbi  = __builtin_amdgcn_sqrtf(btnD);
    const float sbe  = __builtin_amdgcn_sqrtf(sgD);
    const float sbr  = __builtin_amdgcn_sqrtf(gmD);

    // Stage noise pre-multiplied: per-step diffusion becomes sqrt(P)*w.
    for (int i = threadIdx.x; i < NSTEPS; i += 256) {
        const float4 w = dW[i];
        wbuf[i] = make_float4(w.x * sbi, w.y * sbe, w.z * sbr, 0.0f);
    }

    const int lane = threadIdx.x & 63;
    const int wid  = threadIdx.x >> 6;       // 0,1 = compute; 2,3 = store

    // Compute wave cw owns trajs [block*128 + cw*64 + lane].
    const int t  = wid * 64 + lane;          // LDS traj index (valid wid<2)
    float S=0.f, E=0.f, I=0.f, R=0.f;
    if (wid < 2) {
        const int b = blockIdx.x * TPB + t;
        S = S0[b]; E = E0[b]; I = I0[b]; R = R0[b];
    }

    // Store wave sw handles component pair c0=2*sw, c0+1. Lanes 0-31 ->
    // comp c0, lanes 32-63 -> comp c0+1; each half = 512B contiguous segment.
    const int c0 = (wid - 2) * 2;            // valid for wid>=2
    float* const obase = out + blockIdx.x * TPB
                             + (c0 + (lane >> 5)) * B_TRAJ + (lane & 31) * 4;

    // One SEIR step, fma-fused (R16-validated algebra, absmax 0.0):
    // u = iD+ai = fma(btnD,P, sqrt(P)*wx); Sn=Sc-u; En=Ec+u-v; In=Ic+v-r;
    // Rn=Rc+r. 15 VALU/step, per-step wbuf ds_read (hoist falsified R11/R16).
    #define SEIR_STEP(w, dst)                                                  \
    {                                                                          \
        const float Sc = fmaxf(S, EPS);                                        \
        const float Ec = fmaxf(E, EPS);                                        \
        const float Ic = fmaxf(I, EPS);                                        \
        const float Rc = fmaxf(R, EPS);                                        \
        const float P  = Sc * Ic;                                              \
        const float u  = __builtin_fmaf(btnD, P,                               \
                              __builtin_amdgcn_sqrtf(P)  * (w).x);             \
        const float v  = __builtin_fmaf(sgD, Ec,                               \
                              __builtin_amdgcn_sqrtf(Ec) * (w).y);             \
        const float r  = __builtin_fmaf(gmD, Ic,                               \
                              __builtin_amdgcn_sqrtf(Ic) * (w).z);             \
        const float Sn = Sc - u;                                               \
        const float En = Ec + u - v;                                           \
        const float In = Ic + v - r;                                           \
        const float Rn = Rc + r;                                               \
        (dst)[0][t] = Sn;                                                      \
        (dst)[1][t] = En;                                                      \
        (dst)[2][t] = In;                                                      \
        (dst)[3][t] = Rn;                                                      \
        S = Sn; E = En; I = In; R = Rn;                                        \
    }

    // Compute waves: fill chunk c into ring[c&1] (each wave its 64 trajs).
    #define FILL(c)                                                            \
    {                                                                          \
        const int s0 = (c) * K;                                                \
        float (*rw)[4][TPB] = ring[(c) & 1];                                   \
        _Pragma("unroll")                                                      \
        for (int k = 0; k < K; ++k) {                                          \
            const float4 w = wbuf[s0 + k];                                     \
            SEIR_STEP(w, rw[k]);                                               \
        }                                                                      \
    }

    // Store wave: drain its comp-pair slice of chunk c via register set v.
    // Per step: 1KB contiguous ds_read_b128 + dwordx4 (2 x 512B segments).
    // Alternating v sets across chunks => counted-vmcnt WAR, full chunk-slice
    // of stores in flight permanently (R12 machinery).
    #define STORE_CHUNK(c, v)                                                  \
    {                                                                          \
        const float4* rd = (const float4*)&ring[(c) & 1][0][c0][0];            \
        float* o = obase + (size_t)((c) * K) * (4 * B_TRAJ);                   \
        _Pragma("unroll")                                                      \
        for (int k = 0; k < K; ++k) v[k] = rd[k * TPB + lane];                 \
        _Pragma("unroll")                                                      \
        for (int k = 0; k < K; ++k) {                                          \
            *(float4*)o = v[k];                                                \
            o += 4 * B_TRAJ;                                                   \
        }                                                                      \
    }

    float4 va[K], vb[K];                     // two in-flight store sets

    __syncthreads();                         // noise staged (once; drain ok)

    // ---- prologue: compute waves fill chunk 0 ----
    if (wid < 2) FILL(0);
    barrier_lds_only();

    // ---- pipeline, 2 chunks per iteration (NC even) ----
    for (int cc = 0; cc < NC; cc += 2) {
        if (wid < 2) { FILL(cc + 1); }
        else         { STORE_CHUNK(cc, va); }
        barrier_lds_only();
        if (wid < 2) { if (cc + 2 < NC) FILL(cc + 2); }
        else         { STORE_CHUNK(cc + 1, vb); }
        barrier_lds_only();
    }
    #undef SEIR_STEP
    #undef FILL
    #undef STORE_CHUNK
}

extern "C" void kernel_launch(void* const* d_in, const int* in_sizes, int n_in,
                              void* d_out, int out_size, void* d_ws, size_t ws_size,
                              hipStream_t stream) {
    const float*  beta  = (const float*)d_in[0];
    const float*  sigma = (const float*)d_in[1];
    const float*  gamma = (const float*)d_in[2];
    const float*  S0    = (const float*)d_in[3];
    const float*  E0    = (const float*)d_in[4];
    const float*  I0    = (const float*)d_in[5];
    const float*  R0    = (const float*)d_in[6];
    const float4* dW    = (const float4*)d_in[7];
    float* out = (float*)d_out;

    seir_sde_kernel<<<B_TRAJ / TPB, 256, 0, stream>>>(
        beta, sigma, gamma, S0, E0, I0, R0, dW, out);
}

// Round 19
// 90.625 us; speedup vs baseline: 1.1181x; 1.1181x over previous
//
#include <hip/hip_runtime.h>

// SEIR SDE: B=32768 x 1000 steps -> out[step][4][B] f32 = 524 MB (write-bound).
// Ladder: 242 -> 115.6 -> 97.2 (R7) -> 94.2 (R12) -> 89.45 (R17: 512B store
// segments, comp-pair store waves, 1 block/CU). R18 (fma fusion) regressed:
// it serialized drift behind the sqrt chain -> reverted to R17 algebra.
// R17 residual: 4294 cyc/chunk vs 3660 drain work = 634 cyc/chunk. Last
// clean lever: rendezvous frequency (50 lockstep barriers, each max(fill,
// drain)+jitter). R19 = R17 with K=25 (max feasible: ring 102.4KB + 16KB
// noise = 118.4KB < 160KB; K divides 1000; NC=40 even) -> 20% fewer
// rendezvous, deeper (25-deep) in-flight store window. ONE isolated change.

constexpr int   B_TRAJ  = 32768;
constexpr int   NSTEPS  = 1000;
constexpr int   K       = 25;            // steps per chunk (was 20)
constexpr int   NC      = NSTEPS / K;    // 40 chunks (even)
constexpr int   TPB     = 128;           // trajectories per block
constexpr float DT      = 0.01f;
constexpr float EPS     = 1e-6f;
constexpr float INV_N   = 1.0f / 10000.0f;

// Barrier without vmcnt drain: LDS ordering only; global stores stay in
// flight across chunk boundaries.
__device__ __forceinline__ void barrier_lds_only() {
    asm volatile("s_waitcnt lgkmcnt(0)" ::: "memory");
    __builtin_amdgcn_s_barrier();
    asm volatile("" ::: "memory");
}

__global__ __launch_bounds__(256) void seir_sde_kernel(
    const float* __restrict__ beta,
    const float* __restrict__ sigma,
    const float* __restrict__ gamma,
    const float* __restrict__ S0,
    const float* __restrict__ E0,
    const float* __restrict__ I0,
    const float* __restrict__ R0,
    const float4* __restrict__ dW,   // [NSTEPS] raw (w0,w1,w2,w3)
    float* __restrict__ out)         // [NSTEPS][4][B_TRAJ]
{
    __shared__ float4 wbuf[NSTEPS];          // pre-scaled noise, 16 KB
    __shared__ float  ring[2][K][4][TPB];    // SoA chunk ring, 102.4 KB
                                             // 118.4 KB total -> 1 block/CU

    // Folded constants (3 scalar loads, once, all threads).
    const float btnD = beta[0] * INV_N * DT; // (beta/N)*DT
    const float sgD  = sigma[0] * DT;        // sigma*DT
    const float gmD  = gamma[0] * DT;        // gamma*DT
    const float sbi  = __builtin_amdgcn_sqrtf(btnD);
    const float sbe  = __builtin_amdgcn_sqrtf(sgD);
    const float sbr  = __builtin_amdgcn_sqrtf(gmD);

    // Stage noise pre-multiplied: per-step diffusion becomes sqrt(P)*w.
    for (int i = threadIdx.x; i < NSTEPS; i += 256) {
        const float4 w = dW[i];
        wbuf[i] = make_float4(w.x * sbi, w.y * sbe, w.z * sbr, 0.0f);
    }

    const int lane = threadIdx.x & 63;
    const int wid  = threadIdx.x >> 6;       // 0,1 = compute; 2,3 = store

    // Compute wave cw owns trajs [block*128 + cw*64 + lane].
    const int t  = wid * 64 + lane;          // LDS traj index (valid wid<2)
    float S=0.f, E=0.f, I=0.f, R=0.f;
    if (wid < 2) {
        const int b = blockIdx.x * TPB + t;
        S = S0[b]; E = E0[b]; I = I0[b]; R = R0[b];
    }

    // Store wave sw handles component pair c0=2*sw, c0+1. Lanes 0-31 ->
    // comp c0, lanes 32-63 -> comp c0+1; each half = 512B contiguous segment.
    const int c0 = (wid - 2) * 2;            // valid for wid>=2
    float* const obase = out + blockIdx.x * TPB
                             + (c0 + (lane >> 5)) * B_TRAJ + (lane & 31) * 4;

    // One SEIR step, verbatim R17/R12 (validated absmax 0.0): parallel drift
    // and diffusion sub-chains; diffusion = sqrt(P)*w with sqrt(const*DT)
    // folded into wbuf at staging.
    #define SEIR_STEP(w, dst)                                                  \
    {                                                                          \
        const float Sc = fmaxf(S, EPS);                                        \
        const float Ec = fmaxf(E, EPS);                                        \
        const float Ic = fmaxf(I, EPS);                                        \
        const float Rc = fmaxf(R, EPS);                                        \
        const float P  = Sc * Ic;                                              \
        const float iD = btnD * P;                                             \
        const float eD = sgD * Ec;                                             \
        const float rD = gmD * Ic;                                             \
        const float ai = __builtin_amdgcn_sqrtf(P)  * (w).x;                   \
        const float ae = __builtin_amdgcn_sqrtf(Ec) * (w).y;                   \
        const float ar = __builtin_amdgcn_sqrtf(Ic) * (w).z;                   \
        const float Sn = Sc - iD - ai;                                         \
        const float En = Ec + iD - eD + ai - ae;                               \
        const float In = Ic + eD - rD + ae - ar;                               \
        const float Rn = Rc + rD + ar;                                         \
        (dst)[0][t] = Sn;                                                      \
        (dst)[1][t] = En;                                                      \
        (dst)[2][t] = In;                                                      \
        (dst)[3][t] = Rn;                                                      \
        S = Sn; E = En; I = In; R = Rn;                                        \
    }

    // Compute waves: fill chunk c into ring[c&1] (each wave its 64 trajs).
    #define FILL(c)                                                            \
    {                                                                          \
        const int s0 = (c) * K;                                                \
        float (*rw)[4][TPB] = ring[(c) & 1];                                   \
        _Pragma("unroll")                                                      \
        for (int k = 0; k < K; ++k) {                                          \
            const float4 w = wbuf[s0 + k];                                     \
            SEIR_STEP(w, rw[k]);                                               \
        }                                                                      \
    }

    // Store wave: drain its comp-pair slice of chunk c via register set v.
    // Per step: 1KB contiguous ds_read_b128 + dwordx4 (2 x 512B segments).
    // Alternating v sets across chunks => counted-vmcnt WAR, full chunk-slice
    // of stores in flight permanently (R12 machinery).
    #define STORE_CHUNK(c, v)                                                  \
    {                                                                          \
        const float4* rd = (const float4*)&ring[(c) & 1][0][c0][0];            \
        float* o = obase + (size_t)((c) * K) * (4 * B_TRAJ);                   \
        _Pragma("unroll")                                                      \
        for (int k = 0; k < K; ++k) v[k] = rd[k * TPB + lane];                 \
        _Pragma("unroll")                                                      \
        for (int k = 0; k < K; ++k) {                                          \
            *(float4*)o = v[k];                                                \
            o += 4 * B_TRAJ;                                                   \
        }                                                                      \
    }

    float4 va[K], vb[K];                     // two in-flight store sets

    __syncthreads();                         // noise staged (once; drain ok)

    // ---- prologue: compute waves fill chunk 0 ----
    if (wid < 2) FILL(0);
    barrier_lds_only();

    // ---- pipeline, 2 chunks per iteration (NC even) ----
    for (int cc = 0; cc < NC; cc += 2) {
        if (wid < 2) { FILL(cc + 1); }
        else         { STORE_CHUNK(cc, va); }
        barrier_lds_only();
        if (wid < 2) { if (cc + 2 < NC) FILL(cc + 2); }
        else         { STORE_CHUNK(cc + 1, vb); }
        barrier_lds_only();
    }
    #undef SEIR_STEP
    #undef FILL
    #undef STORE_CHUNK
}

extern "C" void kernel_launch(void* const* d_in, const int* in_sizes, int n_in,
                              void* d_out, int out_size, void* d_ws, size_t ws_size,
                              hipStream_t stream) {
    const float*  beta  = (const float*)d_in[0];
    const float*  sigma = (const float*)d_in[1];
    const float*  gamma = (const float*)d_in[2];
    const float*  S0    = (const float*)d_in[3];
    const float*  E0    = (const float*)d_in[4];
    const float*  I0    = (const float*)d_in[5];
    const float*  R0    = (const float*)d_in[6];
    const float4* dW    = (const float4*)d_in[7];
    float* out = (float*)d_out;

    seir_sde_kernel<<<B_TRAJ / TPB, 256, 0, stream>>>(
        beta, sigma, gamma, S0, E0, I0, R0, dW, out);
}

// Round 20
// 89.214 us; speedup vs baseline: 1.1358x; 1.0158x over previous
//
#include <hip/hip_runtime.h>

// SEIR SDE: B=32768 x 1000 steps -> out[step][4][B] f32 = 524 MB (write-bound).
// FINAL (R17 config, 89.45us): 256 blocks (1/CU via 96KB LDS), block=256 =
// 2 compute waves (ILP=1, 64 trajs each) + 2 store waves (component-pair
// split, 512B contiguous segments, va/vb double reg-sets keeping a full
// chunk of stores in flight across lds-only barriers). 5.86 TB/s effective =
// 85% of in-situ fillBuffer rate on this 4-stream 512B-segment pattern.
// Falsified levers: prefetch depth (R3), barrier vmcnt drain (R8), SMEM noise
// (R9), ILP2-single-wave (R10/R15), compute-LDS removal (R11), noise hoist
// (R11/R16), store K-slice split (R13), XCD swizzle (R14), fma fusion (R18:
// chain depth > op count), K=25 window/rendezvous (R19). 512B segment is the
// layout max: wider needs 256 trajs/block -> 128 blocks -> half the CUs idle.

constexpr int   B_TRAJ  = 32768;
constexpr int   NSTEPS  = 1000;
constexpr int   K       = 20;            // steps per chunk
constexpr int   NC      = NSTEPS / K;    // 50 chunks (even)
constexpr int   TPB     = 128;           // trajectories per block
constexpr float DT      = 0.01f;
constexpr float EPS     = 1e-6f;
constexpr float INV_N   = 1.0f / 10000.0f;

// Barrier without vmcnt drain: LDS ordering only; global stores stay in
// flight across chunk boundaries.
__device__ __forceinline__ void barrier_lds_only() {
    asm volatile("s_waitcnt lgkmcnt(0)" ::: "memory");
    __builtin_amdgcn_s_barrier();
    asm volatile("" ::: "memory");
}

__global__ __launch_bounds__(256) void seir_sde_kernel(
    const float* __restrict__ beta,
    const float* __restrict__ sigma,
    const float* __restrict__ gamma,
    const float* __restrict__ S0,
    const float* __restrict__ E0,
    const float* __restrict__ I0,
    const float* __restrict__ R0,
    const float4* __restrict__ dW,   // [NSTEPS] raw (w0,w1,w2,w3)
    float* __restrict__ out)         // [NSTEPS][4][B_TRAJ]
{
    __shared__ float4 wbuf[NSTEPS];          // pre-scaled noise, 16 KB
    __shared__ float  ring[2][K][4][TPB];    // SoA chunk ring, 80 KB
                                             // 96 KB total -> 1 block/CU

    // Folded constants (3 scalar loads, once, all threads).
    const float btnD = beta[0] * INV_N * DT; // (beta/N)*DT
    const float sgD  = sigma[0] * DT;        // sigma*DT
    const float gmD  = gamma[0] * DT;        // gamma*DT
    const float sbi  = __builtin_amdgcn_sqrtf(btnD);
    const float sbe  = __builtin_amdgcn_sqrtf(sgD);
    const float sbr  = __builtin_amdgcn_sqrtf(gmD);

    // Stage noise pre-multiplied: per-step diffusion becomes sqrt(P)*w.
    for (int i = threadIdx.x; i < NSTEPS; i += 256) {
        const float4 w = dW[i];
        wbuf[i] = make_float4(w.x * sbi, w.y * sbe, w.z * sbr, 0.0f);
    }

    const int lane = threadIdx.x & 63;
    const int wid  = threadIdx.x >> 6;       // 0,1 = compute; 2,3 = store

    // Compute wave cw owns trajs [block*128 + cw*64 + lane].
    const int t  = wid * 64 + lane;          // LDS traj index (valid wid<2)
    float S=0.f, E=0.f, I=0.f, R=0.f;
    if (wid < 2) {
        const int b = blockIdx.x * TPB + t;
        S = S0[b]; E = E0[b]; I = I0[b]; R = R0[b];
    }

    // Store wave sw handles component pair c0=2*sw, c0+1. Lanes 0-31 ->
    // comp c0, lanes 32-63 -> comp c0+1; each half = 512B contiguous segment.
    const int c0 = (wid - 2) * 2;            // valid for wid>=2
    float* const obase = out + blockIdx.x * TPB
                             + (c0 + (lane >> 5)) * B_TRAJ + (lane & 31) * 4;

    // One SEIR step (validated absmax 0.0): parallel drift and diffusion
    // sub-chains; diffusion = sqrt(P)*w with sqrt(const*DT) folded into wbuf.
    #define SEIR_STEP(w, dst)                                                  \
    {                                                                          \
        const float Sc = fmaxf(S, EPS);                                        \
        const float Ec = fmaxf(E, EPS);                                        \
        const float Ic = fmaxf(I, EPS);                                        \
        const float Rc = fmaxf(R, EPS);                                        \
        const float P  = Sc * Ic;                                              \
        const float iD = btnD * P;                                             \
        const float eD = sgD * Ec;                                             \
        const float rD = gmD * Ic;                                             \
        const float ai = __builtin_amdgcn_sqrtf(P)  * (w).x;                   \
        const float ae = __builtin_amdgcn_sqrtf(Ec) * (w).y;                   \
        const float ar = __builtin_amdgcn_sqrtf(Ic) * (w).z;                   \
        const float Sn = Sc - iD - ai;                                         \
        const float En = Ec + iD - eD + ai - ae;                               \
        const float In = Ic + eD - rD + ae - ar;                               \
        const float Rn = Rc + rD + ar;                                         \
        (dst)[0][t] = Sn;                                                      \
        (dst)[1][t] = En;                                                      \
        (dst)[2][t] = In;                                                      \
        (dst)[3][t] = Rn;                                                      \
        S = Sn; E = En; I = In; R = Rn;                                        \
    }

    // Compute waves: fill chunk c into ring[c&1] (each wave its 64 trajs).
    #define FILL(c)                                                            \
    {                                                                          \
        const int s0 = (c) * K;                                                \
        float (*rw)[4][TPB] = ring[(c) & 1];                                   \
        _Pragma("unroll")                                                      \
        for (int k = 0; k < K; ++k) {                                          \
            const float4 w = wbuf[s0 + k];                                     \
            SEIR_STEP(w, rw[k]);                                               \
        }                                                                      \
    }

    // Store wave: drain its comp-pair slice of chunk c via register set v.
    // Per step: 1KB contiguous ds_read_b128 + dwordx4 (2 x 512B segments).
    // Alternating v sets across chunks => counted-vmcnt WAR, full chunk-slice
    // of stores in flight permanently.
    #define STORE_CHUNK(c, v)                                                  \
    {                                                                          \
        const float4* rd = (const float4*)&ring[(c) & 1][0][c0][0];            \
        float* o = obase + (size_t)((c) * K) * (4 * B_TRAJ);                   \
        _Pragma("unroll")                                                      \
        for (int k = 0; k < K; ++k) v[k] = rd[k * TPB + lane];                 \
        _Pragma("unroll")                                                      \
        for (int k = 0; k < K; ++k) {                                          \
            *(float4*)o = v[k];                                                \
            o += 4 * B_TRAJ;                                                   \
        }                                                                      \
    }

    float4 va[K], vb[K];                     // two in-flight store sets

    __syncthreads();                         // noise staged (once; drain ok)

    // ---- prologue: compute waves fill chunk 0 ----
    if (wid < 2) FILL(0);
    barrier_lds_only();

    // ---- pipeline, 2 chunks per iteration (NC even) ----
    for (int cc = 0; cc < NC; cc += 2) {
        if (wid < 2) { FILL(cc + 1); }
        else         { STORE_CHUNK(cc, va); }
        barrier_lds_only();
        if (wid < 2) { if (cc + 2 < NC) FILL(cc + 2); }
        else         { STORE_CHUNK(cc + 1, vb); }
        barrier_lds_only();
    }
    #undef SEIR_STEP
    #undef FILL
    #undef STORE_CHUNK
}

extern "C" void kernel_launch(void* const* d_in, const int* in_sizes, int n_in,
                              void* d_out, int out_size, void* d_ws, size_t ws_size,
                              hipStream_t stream) {
    const float*  beta  = (const float*)d_in[0];
    const float*  sigma = (const float*)d_in[1];
    const float*  gamma = (const float*)d_in[2];
    const float*  S0    = (const float*)d_in[3];
    const float*  E0    = (const float*)d_in[4];
    const float*  I0    = (const float*)d_in[5];
    const float*  R0    = (const float*)d_in[6];
    const float4* dW    = (const float4*)d_in[7];
    float* out = (float*)d_out;

    seir_sde_kernel<<<B_TRAJ / TPB, 256, 0, stream>>>(
        beta, sigma, gamma, S0, E0, I0, R0, dW, out);
}